// Round 6
// baseline (83.436 us; speedup 1.0000x reference)
//
#include <hip/hip_runtime.h>

// ARIMA(2,1,2) residual recurrence — single-wave blocks, fence-only sync,
// double-buffered LDS + 2-deep register prefetch.
//
// eps_j = (y[j+3]-y[j+2]-mu-phi0*y[j+2]-phi1*y[j+1]) - q0*eps_{j-1} - q1*eps_{j-2}
// out[b,0..4092] = eps, out[b,4093..4094] = 0.
//
// R6 vs R5: R5 still stalled ~600cyc/tile at lds_write (loads issued only one
// dump earlier). Now: 2 LDS buffers (tile parity) + 2 stage reg-sets; tile
// t+1's global loads are issued TWO iterations before consumption, so the
// vmcnt wait at lds_write is fully covered by compute(t)+dump(t).
// TILE=32 keeps 2-buf LDS at 16.6KB -> 9 blocks/CU >= the 8 grid-limited waves.

#define TSEQ   4096
#define TOUT   4095
#define NJ     4093
#define CHUNK  256
#define NCHUNK 16
#define TILE   32
#define PITCH  65     // row dimension (64 rows + 1 pad)
#define WARM   61     // tile0 yields 29 outputs; mid-chunks: NT = 10 tiles

// single-wave block: cross-lane LDS ordering needs only a DS-complete fence
#define LGKM_FENCE() do { \
    asm volatile("s_waitcnt lgkmcnt(0)" ::: "memory"); \
    __builtin_amdgcn_sched_barrier(0); \
} while (0)

// issue 8 coalesced float4 loads (64 rows x cols TBASE..TBASE+31) into SET
#define STAGE(SET, SD, TBASE) do { \
    int off_ = (TBASE) + scol; \
    if (off_ > TSEQ - 4) off_ = TSEQ - 4;   /* tail clamp (c==15 last tile) */ \
    SD = off_ - (TBASE);                    /* destination-corrected col    */ \
    _Pragma("unroll") \
    for (int qq = 0; qq < 8; ++qq) { \
        const int r_ = qq * 8 + srow; \
        SET[qq] = *reinterpret_cast<const float4*>(&Y[(size_t)r_ * TSEQ + off_]); \
    } \
} while (0)

// SET regs -> LDS buffer BI, transposed (compiler inserts counted vmcnt wait)
#define LDSW(SET, SD, BI) do { \
    _Pragma("unroll") \
    for (int qq = 0; qq < 8; ++qq) { \
        const int r_ = qq * 8 + srow; \
        lds[BI][SD + 0][r_] = SET[qq].x; \
        lds[BI][SD + 1][r_] = SET[qq].y; \
        lds[BI][SD + 2][r_] = SET[qq].z; \
        lds[BI][SD + 3][r_] = SET[qq].w; \
    } \
} while (0)

__global__ __launch_bounds__(64) void arima_eps_db(
    const float* __restrict__ y,
    const float* __restrict__ phi,
    const float* __restrict__ theta,
    const float* __restrict__ mu,
    float* __restrict__ out)
{
    __shared__ float lds[2][TILE][PITCH];   // [buf][col][row(=lane)]

    const int lane = threadIdx.x;
    const int g = blockIdx.x >> 4;          // 64-row group
    const int c = blockIdx.x & (NCHUNK - 1);
    const int rowbase = g * 64;

    const float p0 = phi[0], p1v = phi[1];
    const float q0 = theta[0], q1 = theta[1];
    const float m  = mu[0];
    const float c1 = 1.0f + p0;             // tg = y[j+3]-c1*y[j+2]-p1*y[j+1]-m
    const float A  = q0 * q0 - q1;          // composed 2-step coefficients
    const float Bc = q0 * q1;

    const float* __restrict__ Y = y + (size_t)rowbase * TSEQ;
    float* __restrict__ O       = out + (size_t)rowbase * TOUT;

    const int j0 = c * CHUNK;
    const int j1 = min(j0 + CHUNK, NJ);
    const int jw = max(j0 - WARM, 0);
    const int NT = (j1 + 3 - jw + TILE - 1) / TILE;  // 9 (c=0) or 10

    const int srow = lane >> 3;             // 0..7
    const int scol = (lane & 7) << 2;       // 0,4,...,28

    float4 s0[8], s1[8];
    int sd0, sd1;

    // recurrence state
    float yp1, yp2;                         // y[j+2], y[j+1]
    float e1 = 0.f, e2 = 0.f, e3 = 0.f;
    float tp = 0.f;                         // previous tg

    // 8 composed steps on buffer Bf: cols cb..cb+7 (y in, eps out in place)
    auto step8 = [&](float (*Bf)[PITCH], int cb) {
        float yv[8];
        #pragma unroll
        for (int k = 0; k < 8; ++k) yv[k] = Bf[cb + k][lane];
        float tg[8];
        {
            float pa = yp2, pb = yp1;
            #pragma unroll
            for (int k = 0; k < 8; ++k) {
                float t = __builtin_fmaf(-c1, pb, yv[k]);
                t = __builtin_fmaf(-p1v, pa, t);
                tg[k] = t - m;
                pa = pb; pb = yv[k];
            }
        }
        yp2 = yv[6]; yp1 = yv[7];
        float T[8];
        T[0] = __builtin_fmaf(-q0, tp, tg[0]);
        #pragma unroll
        for (int k = 1; k < 8; ++k) T[k] = __builtin_fmaf(-q0, tg[k - 1], tg[k]);
        tp = tg[7];
        float ev[8];
        ev[0] = __builtin_fmaf(A, e2,    __builtin_fmaf(Bc, e3,    T[0]));
        ev[1] = __builtin_fmaf(A, e1,    __builtin_fmaf(Bc, e2,    T[1]));
        ev[2] = __builtin_fmaf(A, ev[0], __builtin_fmaf(Bc, e1,    T[2]));
        ev[3] = __builtin_fmaf(A, ev[1], __builtin_fmaf(Bc, ev[0], T[3]));
        ev[4] = __builtin_fmaf(A, ev[2], __builtin_fmaf(Bc, ev[1], T[4]));
        ev[5] = __builtin_fmaf(A, ev[3], __builtin_fmaf(Bc, ev[2], T[5]));
        ev[6] = __builtin_fmaf(A, ev[4], __builtin_fmaf(Bc, ev[3], T[6]));
        ev[7] = __builtin_fmaf(A, ev[5], __builtin_fmaf(Bc, ev[4], T[7]));
        e3 = ev[5]; e2 = ev[6]; e1 = ev[7];
        #pragma unroll
        for (int k = 0; k < 8; ++k) Bf[cb + k][lane] = ev[k];
    };

    // coalesced dump of eps cols [max(jt,j0), min(jcur,j1)) from buffer Bf
    auto dump = [&](float (*Bf)[PITCH], int jt, int jcur, int tb) {
        const int jd  = max(jt, j0);
        const int je  = min(jcur, j1);
        const int cnt = je - jd;
        if (cnt <= 0) return;
        const int dcol = jd + 3 - tb;
        const int col  = lane & 31;
        const int rh   = lane >> 5;
        const bool on  = col < cnt;
        #pragma unroll
        for (int r2 = 0; r2 < 32; ++r2) {
            const int r = r2 * 2 + rh;
            if (on) O[(size_t)r * TOUT + jd + col] = Bf[dcol + col][r];
        }
    };

    // ---- prologue: tile0 -> buf0; prefetch tiles 1,2 ----
    int tb = jw;
    STAGE(s0, sd0, tb);
    LDSW(s0, sd0, 0);
    if (NT > 1) STAGE(s1, sd1, tb + TILE);
    if (NT > 2) STAGE(s0, sd0, tb + 2 * TILE);
    LGKM_FENCE();
    {   // seed: cols 0..7 of buf0 (5 direct-form outputs), then 3x step8
        float yv0[8];
        #pragma unroll
        for (int k = 0; k < 8; ++k) yv0[k] = lds[0][k][lane];
        yp2 = yv0[1]; yp1 = yv0[2];
        float ev[5];
        #pragma unroll
        for (int k = 3; k < 8; ++k) {
            float t = __builtin_fmaf(-c1, yp1, yv0[k]);
            t = __builtin_fmaf(-p1v, yp2, t);
            t -= m;
            float e = __builtin_fmaf(-q0, e1, t);
            e = __builtin_fmaf(-q1, e2, e);
            ev[k - 3] = e;
            e3 = e2; e2 = e1; e1 = e;
            tp = t;
            yp2 = yp1; yp1 = yv0[k];
        }
        #pragma unroll
        for (int k = 3; k < 8; ++k) lds[0][k][lane] = ev[k - 3];
        step8(lds[0], 8); step8(lds[0], 16); step8(lds[0], 24);
    }
    LGKM_FENCE();
    int jt = jw;
    int j  = jw + TILE - 3;                 // 29 outputs in tile 0

    // ---- steady state: dump(t); write t+1; stage t+3; compute t+1 ----
    for (int t = 0; t + 1 < NT; ++t) {
        dump(lds[t & 1], jt, j, tb);
        if (((t + 1) & 1) == 0) {
            LDSW(s0, sd0, 0);
            if (t + 3 < NT) STAGE(s0, sd0, tb + 3 * TILE);
        } else {
            LDSW(s1, sd1, 1);
            if (t + 3 < NT) STAGE(s1, sd1, tb + 3 * TILE);
        }
        LGKM_FENCE();
        tb += TILE;
        jt = tb - 3;
        {
            float (*Bf)[PITCH] = lds[(t + 1) & 1];
            step8(Bf, 0); step8(Bf, 8); step8(Bf, 16); step8(Bf, 24);
        }
        j = jt + TILE;
        LGKM_FENCE();
    }
    dump(lds[(NT - 1) & 1], jt, j, tb);

    // trailing Q zeros (harness poisons d_out)
    if (c == NCHUNK - 1) {
        O[(size_t)lane * TOUT + NJ]     = 0.f;
        O[(size_t)lane * TOUT + NJ + 1] = 0.f;
    }
}

extern "C" void kernel_launch(void* const* d_in, const int* in_sizes, int n_in,
                              void* d_out, int out_size, void* d_ws, size_t ws_size,
                              hipStream_t stream) {
    const float* y     = (const float*)d_in[0];
    const float* phi   = (const float*)d_in[1];
    const float* theta = (const float*)d_in[2];
    const float* mu    = (const float*)d_in[3];
    float* out         = (float*)d_out;

    int B = in_sizes[0] / TSEQ;                 // 8192
    int rowgroups = B / 64;                     // 128
    dim3 block(64);
    dim3 grid(rowgroups * NCHUNK);              // 2048 single-wave blocks
    arima_eps_db<<<grid, block, 0, stream>>>(y, phi, theta, mu, out);
}

// Round 7
// 71.779 us; speedup vs baseline: 1.1624x; 1.1624x over previous
//
#include <hip/hip_runtime.h>

// ARIMA(2,1,2) residual recurrence — R2 structure (best measured, 64.3us),
// with exact-tiling warm-up and composed 2-step eps chain.
//
// eps_j = (y[j+3]-y[j+2]-mu-phi0*y[j+2]-phi1*y[j+1]) - q0*eps_{j-1} - q1*eps_{j-2}
// out[b,0..4092] = eps, out[b,4093..4094] = 0.
//
// R7 vs R2: WARM=61 -> chunk covers exactly 5x64 cols (R2 burned a 6th tile
// for 3 outputs); composed chain e[k]=A*e[k-2]+Bc*e[k-3]+(tg[k]-q0*tg[k-1]);
// dump uses 32 two-row store instrs. Plain __syncthreads (R5 showed manual
// fences + sched_barrier defeat the compiler's own scheduling).
// Session-invariant: delivered BW ~3.5-3.9 TB/s across all 6 structures
// (occupancy x2 and deep pipelining both neutral) -> minimize traffic+rounds.

#define TSEQ   4096
#define TOUT   4095
#define NJ     4093
#define CHUNK  256
#define NCHUNK 16
#define TILE   64
#define PITCH  65
#define WARM   61     // tile0 yields 61 outputs; 61+4*64 = 317 ... 5 tiles exact

__global__ __launch_bounds__(64) void arima_eps_r7(
    const float* __restrict__ y,
    const float* __restrict__ phi,
    const float* __restrict__ theta,
    const float* __restrict__ mu,
    float* __restrict__ out)
{
    __shared__ float lds[TILE][PITCH];   // [col][row(=lane)], 2-way banks=free

    const int lane = threadIdx.x;
    const int g = blockIdx.x >> 4;       // 64-row group
    const int c = blockIdx.x & (NCHUNK - 1);
    const int rowbase = g * 64;

    const float p0 = phi[0], p1v = phi[1];
    const float q0 = theta[0], q1 = theta[1];
    const float m  = mu[0];
    const float c1 = 1.0f + p0;          // tg = y[j+3]-c1*y[j+2]-p1*y[j+1]-m
    const float A  = q0 * q0 - q1;       // composed 2-step coefficients
    const float Bc = q0 * q1;

    const float* __restrict__ Y = y + (size_t)rowbase * TSEQ;
    float* __restrict__ O       = out + (size_t)rowbase * TOUT;

    const int j0 = c * CHUNK;
    const int j1 = min(j0 + CHUNK, NJ);
    const int jw = max(j0 - WARM, 0);

    const int srow = lane >> 4;          // 0..3
    const int scol = (lane & 15) << 2;   // 0,4,...,60

    // global (16 coalesced float4 loads, 64 rows x 64 cols) -> LDS transposed
    auto load_tile = [&](int tbase) {
        int off = tbase + scol;
        if (off > TSEQ - 4) off = TSEQ - 4;   // tail clamp (c==15 last tile)
        const int sd = off - tbase;           // destination-corrected col
        #pragma unroll
        for (int qq = 0; qq < 16; ++qq) {
            const int r = qq * 4 + srow;
            const float4 v = *reinterpret_cast<const float4*>(
                &Y[(size_t)r * TSEQ + off]);
            lds[sd + 0][r] = v.x;
            lds[sd + 1][r] = v.y;
            lds[sd + 2][r] = v.z;
            lds[sd + 3][r] = v.w;
        }
    };

    // recurrence state
    float yp1, yp2;                      // y[j+2], y[j+1]
    float e1 = 0.f, e2 = 0.f, e3 = 0.f;
    float tp = 0.f;                      // previous tg

    // 8 composed steps: lds cols cb..cb+7 (y in, eps out in place)
    auto step8 = [&](int cb) {
        float yv[8];
        #pragma unroll
        for (int k = 0; k < 8; ++k) yv[k] = lds[cb + k][lane];
        float tg[8];
        {
            float pa = yp2, pb = yp1;
            #pragma unroll
            for (int k = 0; k < 8; ++k) {
                float t = __builtin_fmaf(-c1, pb, yv[k]);
                t = __builtin_fmaf(-p1v, pa, t);
                tg[k] = t - m;
                pa = pb; pb = yv[k];
            }
        }
        yp2 = yv[6]; yp1 = yv[7];
        float T[8];
        T[0] = __builtin_fmaf(-q0, tp, tg[0]);
        #pragma unroll
        for (int k = 1; k < 8; ++k) T[k] = __builtin_fmaf(-q0, tg[k - 1], tg[k]);
        tp = tg[7];
        float ev[8];
        ev[0] = __builtin_fmaf(A, e2,    __builtin_fmaf(Bc, e3,    T[0]));
        ev[1] = __builtin_fmaf(A, e1,    __builtin_fmaf(Bc, e2,    T[1]));
        ev[2] = __builtin_fmaf(A, ev[0], __builtin_fmaf(Bc, e1,    T[2]));
        ev[3] = __builtin_fmaf(A, ev[1], __builtin_fmaf(Bc, ev[0], T[3]));
        ev[4] = __builtin_fmaf(A, ev[2], __builtin_fmaf(Bc, ev[1], T[4]));
        ev[5] = __builtin_fmaf(A, ev[3], __builtin_fmaf(Bc, ev[2], T[5]));
        ev[6] = __builtin_fmaf(A, ev[4], __builtin_fmaf(Bc, ev[3], T[6]));
        ev[7] = __builtin_fmaf(A, ev[5], __builtin_fmaf(Bc, ev[4], T[7]));
        e3 = ev[5]; e2 = ev[6]; e1 = ev[7];
        #pragma unroll
        for (int k = 0; k < 8; ++k) lds[cb + k][lane] = ev[k];
    };

    // coalesced dump of eps cols [max(jt,j0), min(jcur,j1)): 2 rows x 32 cols
    auto dump = [&](int jt, int jcur, int tb) {
        const int jd  = max(jt, j0);
        const int je  = min(jcur, j1);
        const int cnt = je - jd;
        if (cnt <= 0) return;
        const int dcol = jd + 3 - tb;
        const int col  = lane & 31;
        const int rh   = lane >> 5;
        const bool on  = col < cnt;
        #pragma unroll
        for (int r2 = 0; r2 < 32; ++r2) {
            const int r = r2 * 2 + rh;
            if (on) O[(size_t)r * TOUT + jd + col] = lds[dcol + col][r];
        }
        if (cnt > 32) {
            const int col2 = col + 32;
            const bool on2 = col2 < cnt;
            #pragma unroll
            for (int r2 = 0; r2 < 32; ++r2) {
                const int r = r2 * 2 + rh;
                if (on2) O[(size_t)r * TOUT + jd + col2] = lds[dcol + col2][r];
            }
        }
    };

    // ---- tile 0: cols jw..jw+63; seed then 61 outputs ----
    int tb = jw;
    load_tile(tb);
    __syncthreads();
    {   // seed: cols 0..7 (direct form, 5 outputs), then 7x step8
        float yv0[8];
        #pragma unroll
        for (int k = 0; k < 8; ++k) yv0[k] = lds[k][lane];
        yp2 = yv0[1]; yp1 = yv0[2];
        float ev[5];
        #pragma unroll
        for (int k = 3; k < 8; ++k) {
            float t = __builtin_fmaf(-c1, yp1, yv0[k]);
            t = __builtin_fmaf(-p1v, yp2, t);
            t -= m;
            float e = __builtin_fmaf(-q0, e1, t);
            e = __builtin_fmaf(-q1, e2, e);
            ev[k - 3] = e;
            e3 = e2; e2 = e1; e1 = e;
            tp = t;
            yp2 = yp1; yp1 = yv0[k];
        }
        #pragma unroll
        for (int k = 3; k < 8; ++k) lds[k][lane] = ev[k - 3];
    }
    step8(8); step8(16); step8(24); step8(32); step8(40); step8(48); step8(56);
    int jt = jw;
    int j  = jw + TILE - 3;              // 61 outputs in tile 0
    __syncthreads();
    dump(jt, j, tb);

    // ---- 4 more tiles of exactly 64 outputs ----
    while (j < j1) {
        __syncthreads();                 // dump reads done before overwrite
        tb += TILE;
        load_tile(tb);
        __syncthreads();
        jt = tb - 3;
        step8(0); step8(8); step8(16); step8(24);
        step8(32); step8(40); step8(48); step8(56);
        j = jt + TILE;
        __syncthreads();
        dump(jt, j, tb);
    }

    // trailing Q zeros (harness poisons d_out)
    if (c == NCHUNK - 1) {
        O[(size_t)lane * TOUT + NJ]     = 0.f;
        O[(size_t)lane * TOUT + NJ + 1] = 0.f;
    }
}

extern "C" void kernel_launch(void* const* d_in, const int* in_sizes, int n_in,
                              void* d_out, int out_size, void* d_ws, size_t ws_size,
                              hipStream_t stream) {
    const float* y     = (const float*)d_in[0];
    const float* phi   = (const float*)d_in[1];
    const float* theta = (const float*)d_in[2];
    const float* mu    = (const float*)d_in[3];
    float* out         = (float*)d_out;

    int B = in_sizes[0] / TSEQ;                 // 8192
    int rowgroups = B / 64;                     // 128
    dim3 block(64);
    dim3 grid(rowgroups * NCHUNK);              // 2048 single-wave blocks
    arima_eps_r7<<<grid, block, 0, stream>>>(y, phi, theta, mu, out);
}